// Round 1
// baseline (272.247 us; speedup 1.0000x reference)
//
#include <hip/hip_runtime.h>
#include <math.h>

#define SEQ   8192
#define DIM   2048
#define NH    16
#define DH    128
#define PD    512

static constexpr float LN_EPS = 1e-5f;
static constexpr float SCALE  = 0.08838834764831845f; // 1/sqrt(128)

// ---- workspace layout (in floats) ----
static constexpr size_t OFF_QW   = 0;                       // 16*2048
static constexpr size_t OFF_QB   = OFF_QW + 16*2048;        // 16
static constexpr size_t OFF_LOG  = 32800;                   // 16*8192
static constexpr size_t OFF_ATT  = OFF_LOG + 16*8192;       // 8192*16 (transposed [s][h])
static constexpr size_t OFF_PCTX = OFF_ATT + 8192*16;       // 32*16*2048
static constexpr size_t OFF_CTX  = OFF_PCTX + 32*16*2048;   // 16*2048
static constexpr size_t OFF_X1   = OFF_CTX + 16*2048;       // 2048
static constexpr size_t OFF_H1R  = OFF_X1 + 2048;           // 512
static constexpr size_t OFF_H1   = OFF_H1R + 512;           // 512
static constexpr size_t OFF_X1F  = OFF_H1 + 512;            // 2048

// qW[h][j] = sum_d q[h*128+d] * W_kv[(h*128+d)*DIM + j]
__global__ __launch_bounds__(256) void k_qw(const float* __restrict__ q,
                                            const float* __restrict__ Wkv,
                                            float* __restrict__ qW) {
    int h = blockIdx.x >> 3, jc = blockIdx.x & 7;
    int j = jc * 256 + threadIdx.x;
    const float* wcol = Wkv + (size_t)(h * DH) * DIM + j;
    const float* qh = q + h * DH;
    float acc = 0.f;
#pragma unroll 8
    for (int d = 0; d < DH; ++d)
        acc += qh[d] * wcol[(size_t)d * DIM];
    qW[h * DIM + j] = acc;
}

// qb[h] = sum_d q[h*128+d]*b_kv[h*128+d]
__global__ void k_qb(const float* __restrict__ q, const float* __restrict__ bkv,
                     float* __restrict__ qb) {
    int h = blockIdx.x, t = threadIdx.x;
    float p = q[h*DH + t] * bkv[h*DH + t] + q[h*DH + 64 + t] * bkv[h*DH + 64 + t];
    for (int off = 32; off; off >>= 1) p += __shfl_down(p, off);
    if (t == 0) qb[h] = p;
}

// logits[h][s] = (x[s]·qW[h] + qb[h]) * SCALE
// block = 256 threads, thread t owns cols [t*8, t*8+8); 32 rows/block; grid 256
__global__ __launch_bounds__(256) void k_logits(const float* __restrict__ x,
                                                const float* __restrict__ qW,
                                                const float* __restrict__ qb,
                                                float* __restrict__ logits) {
    const int t = threadIdx.x;
    const int j0 = t * 8;
    float4 qw0[NH], qw1[NH];
#pragma unroll
    for (int h = 0; h < NH; ++h) {
        qw0[h] = *(const float4*)&qW[h * DIM + j0];
        qw1[h] = *(const float4*)&qW[h * DIM + j0 + 4];
    }
    __shared__ float wred[4][NH];
    const int lane = t & 63, w = t >> 6;
    // bit-reversed-nibble head assignment for the fold-reduce
    const int head = (((lane & 1) << 3) | (((lane >> 1) & 1) << 2) |
                      (((lane >> 2) & 1) << 1) | ((lane >> 3) & 1));
    int s0 = blockIdx.x * 32;
    for (int r = 0; r < 32; ++r) {
        int s = s0 + r;
        float4 xa = *(const float4*)&x[(size_t)s * DIM + j0];
        float4 xb = *(const float4*)&x[(size_t)s * DIM + j0 + 4];
        float p[NH];
#pragma unroll
        for (int h = 0; h < NH; ++h) {
            p[h] = xa.x*qw0[h].x + xa.y*qw0[h].y + xa.z*qw0[h].z + xa.w*qw0[h].w
                 + xb.x*qw1[h].x + xb.y*qw1[h].y + xb.z*qw1[h].z + xb.w*qw1[h].w;
        }
        // fold-reduce: 16 values x 64 lanes -> 1 value/lane (head = bitrev nibble)
#pragma unroll
        for (int k = 0; k < 4; ++k) {
            const int m = 1 << k;
            const int n = 16 >> k;
            const bool hi = (lane >> k) & 1;
#pragma unroll
            for (int i = 0; i < (n >> 1); ++i) {
                float a = p[i], b = p[i + (n >> 1)];
                float send = hi ? a : b;
                float recv = __shfl_xor(send, m);
                p[i] = (hi ? b : a) + recv;
            }
        }
        float v = p[0];
        v += __shfl_xor(v, 16);
        v += __shfl_xor(v, 32);
        if (lane < 16) wred[w][head] = v;
        __syncthreads();
        if (t < NH) {
            float l = wred[0][t] + wred[1][t] + wred[2][t] + wred[3][t];
            logits[t * SEQ + s] = (l + qb[t]) * SCALE;
        }
        __syncthreads();
    }
}

// softmax per head over SEQ; writes transposed attnT[s][h]
__global__ __launch_bounds__(256) void k_softmax(const float* __restrict__ logits,
                                                 float* __restrict__ attnT) {
    int h = blockIdx.x, t = threadIdx.x;
    const float* l = logits + (size_t)h * SEQ;
    __shared__ float red[4];
    float m = -1e30f;
    for (int s = t; s < SEQ; s += 256) m = fmaxf(m, l[s]);
    for (int off = 32; off; off >>= 1) m = fmaxf(m, __shfl_xor(m, off));
    if ((t & 63) == 0) red[t >> 6] = m;
    __syncthreads();
    m = fmaxf(fmaxf(red[0], red[1]), fmaxf(red[2], red[3]));
    float sum = 0.f;
    for (int s = t; s < SEQ; s += 256) sum += __expf(l[s] - m);
    for (int off = 32; off; off >>= 1) sum += __shfl_xor(sum, off);
    __syncthreads();
    if ((t & 63) == 0) red[t >> 6] = sum;
    __syncthreads();
    float inv = 1.0f / (red[0] + red[1] + red[2] + red[3]);
    for (int s = t; s < SEQ; s += 256) attnT[(size_t)s * NH + h] = __expf(l[s] - m) * inv;
}

// partial ctx: pctx[sc][h][j] = sum_{s in chunk sc} attnT[s][h] * x[s][j]
// grid 256: sc = bx>>3 (32 chunks of 256 rows), jc = bx&7 (8 chunks of 256 cols)
__global__ __launch_bounds__(256) void k_ctx(const float* __restrict__ x,
                                             const float* __restrict__ attnT,
                                             float* __restrict__ pctx) {
    int sc = blockIdx.x >> 3, jc = blockIdx.x & 7;
    int j = jc * 256 + threadIdx.x;
    float acc[NH];
#pragma unroll
    for (int h = 0; h < NH; ++h) acc[h] = 0.f;
    int s0 = sc * 256;
    for (int r = 0; r < 256; ++r) {
        int s = s0 + r;
        float xv = x[(size_t)s * DIM + j];
        const float4* ap = (const float4*)(attnT + (size_t)s * NH);
        float4 a0 = ap[0], a1 = ap[1], a2 = ap[2], a3 = ap[3];
        acc[0]  += a0.x * xv; acc[1]  += a0.y * xv; acc[2]  += a0.z * xv; acc[3]  += a0.w * xv;
        acc[4]  += a1.x * xv; acc[5]  += a1.y * xv; acc[6]  += a1.z * xv; acc[7]  += a1.w * xv;
        acc[8]  += a2.x * xv; acc[9]  += a2.y * xv; acc[10] += a2.z * xv; acc[11] += a2.w * xv;
        acc[12] += a3.x * xv; acc[13] += a3.y * xv; acc[14] += a3.z * xv; acc[15] += a3.w * xv;
    }
#pragma unroll
    for (int h = 0; h < NH; ++h)
        pctx[((size_t)(sc * NH + h)) * DIM + j] = acc[h];
}

// ctx[h][j] = sum_sc pctx[sc][h][j]
__global__ __launch_bounds__(256) void k_ctxred(const float* __restrict__ pctx,
                                                float* __restrict__ ctx) {
    int idx = blockIdx.x * 256 + threadIdx.x; // 0..32767
    float s = 0.f;
#pragma unroll 8
    for (int sc = 0; sc < 32; ++sc)
        s += pctx[(size_t)sc * (NH * DIM) + idx];
    ctx[idx] = s;
}

// x1[row] = ctx[row>>7]·W_v[row] + b_kv[DIM+row]; one wave per row, 4 rows/block
__global__ __launch_bounds__(256) void k_x1(const float* __restrict__ Wkv,
                                            const float* __restrict__ bkv,
                                            const float* __restrict__ ctx,
                                            float* __restrict__ x1) {
    int row = blockIdx.x * 4 + (threadIdx.x >> 6);
    int lane = threadIdx.x & 63;
    const float* w = Wkv + (size_t)(DIM + row) * DIM;
    const float* c = ctx + (row >> 7) * DIM;
    float acc = 0.f;
#pragma unroll
    for (int k = 0; k < 8; ++k) {
        int j = k * 256 + lane * 4;
        float4 wv = *(const float4*)&w[j];
        float4 cv = *(const float4*)&c[j];
        acc += wv.x*cv.x + wv.y*cv.y + wv.z*cv.z + wv.w*cv.w;
    }
    for (int off = 32; off; off >>= 1) acc += __shfl_xor(acc, off);
    if (lane == 0) x1[row] = acc + bkv[DIM + row];
}

// h1raw[row] = x1·W_p1[row] + b_p1[row]; one wave per row (512 rows), 4/block
__global__ __launch_bounds__(256) void k_h1(const float* __restrict__ Wp1,
                                            const float* __restrict__ bp1,
                                            const float* __restrict__ x1,
                                            float* __restrict__ h1raw) {
    int row = blockIdx.x * 4 + (threadIdx.x >> 6);
    int lane = threadIdx.x & 63;
    const float* w = Wp1 + (size_t)row * DIM;
    float acc = 0.f;
#pragma unroll
    for (int k = 0; k < 8; ++k) {
        int j = k * 256 + lane * 4;
        float4 wv = *(const float4*)&w[j];
        float4 cv = *(const float4*)&x1[j];
        acc += wv.x*cv.x + wv.y*cv.y + wv.z*cv.z + wv.w*cv.w;
    }
    for (int off = 32; off; off >>= 1) acc += __shfl_xor(acc, off);
    if (lane == 0) h1raw[row] = acc + bp1[row];
}

// LayerNorm + relu over 512 elems; single block of 512
__global__ __launch_bounds__(512) void k_ln(const float* __restrict__ h1raw,
                                            const float* __restrict__ lnw,
                                            const float* __restrict__ lnb,
                                            float* __restrict__ h1) {
    int t = threadIdx.x;
    __shared__ float red[8];
    float v = h1raw[t];
    float s = v;
    for (int off = 32; off; off >>= 1) s += __shfl_xor(s, off);
    if ((t & 63) == 0) red[t >> 6] = s;
    __syncthreads();
    float mu = 0.f;
#pragma unroll
    for (int i = 0; i < 8; ++i) mu += red[i];
    mu *= (1.0f / PD);
    float d = v - mu;
    float s2 = d * d;
    for (int off = 32; off; off >>= 1) s2 += __shfl_xor(s2, off);
    __syncthreads();
    if ((t & 63) == 0) red[t >> 6] = s2;
    __syncthreads();
    float var = 0.f;
#pragma unroll
    for (int i = 0; i < 8; ++i) var += red[i];
    var *= (1.0f / PD);
    float y = d * rsqrtf(var + LN_EPS) * lnw[t] + lnb[t];
    h1[t] = fmaxf(y, 0.f);
}

// x1f[row] = relu(h1)·W_p2[row] + b_p2[row]; one wave per row (2048 rows)
__global__ __launch_bounds__(256) void k_x1f(const float* __restrict__ Wp2,
                                             const float* __restrict__ bp2,
                                             const float* __restrict__ h1,
                                             float* __restrict__ x1f) {
    int row = blockIdx.x * 4 + (threadIdx.x >> 6);
    int lane = threadIdx.x & 63;
    const float* w = Wp2 + (size_t)row * PD;
    float acc = 0.f;
#pragma unroll
    for (int k = 0; k < 2; ++k) {
        int j = k * 256 + lane * 4;
        float4 wv = *(const float4*)&w[j];
        float4 cv = *(const float4*)&h1[j];
        acc += wv.x*cv.x + wv.y*cv.y + wv.z*cv.z + wv.w*cv.w;
    }
    for (int off = 32; off; off >>= 1) acc += __shfl_xor(acc, off);
    if (lane == 0) x1f[row] = acc + bp2[row];
}

// out[s][j] = x[s][j] + x1f[j]
__global__ __launch_bounds__(256) void k_out(const float* __restrict__ x,
                                             const float* __restrict__ x1f,
                                             float* __restrict__ out) {
    size_t i = (size_t)blockIdx.x * 256 + threadIdx.x; // float4 index
    int col4 = (int)(i & 511);
    float4 xv = ((const float4*)x)[i];
    float4 a  = ((const float4*)x1f)[col4];
    float4 o;
    o.x = xv.x + a.x; o.y = xv.y + a.y; o.z = xv.z + a.z; o.w = xv.w + a.w;
    ((float4*)out)[i] = o;
}

extern "C" void kernel_launch(void* const* d_in, const int* in_sizes, int n_in,
                              void* d_out, int out_size, void* d_ws, size_t ws_size,
                              hipStream_t stream) {
    const float* x    = (const float*)d_in[0];
    const float* q    = (const float*)d_in[1];
    const float* Wkv  = (const float*)d_in[2];
    const float* bkv  = (const float*)d_in[3];
    const float* Wp1  = (const float*)d_in[4];
    const float* bp1  = (const float*)d_in[5];
    const float* Wp2  = (const float*)d_in[6];
    const float* bp2  = (const float*)d_in[7];
    const float* lnw  = (const float*)d_in[8];
    const float* lnb  = (const float*)d_in[9];
    float* out = (float*)d_out;
    float* ws  = (float*)d_ws;

    float* qW    = ws + OFF_QW;
    float* qb    = ws + OFF_QB;
    float* logits= ws + OFF_LOG;
    float* attnT = ws + OFF_ATT;
    float* pctx  = ws + OFF_PCTX;
    float* ctx   = ws + OFF_CTX;
    float* x1    = ws + OFF_X1;
    float* h1raw = ws + OFF_H1R;
    float* h1    = ws + OFF_H1;
    float* x1f   = ws + OFF_X1F;

    k_qw     <<<128,   256, 0, stream>>>(q, Wkv, qW);
    k_qb     <<<16,     64, 0, stream>>>(q, bkv, qb);
    k_logits <<<256,   256, 0, stream>>>(x, qW, qb, logits);
    k_softmax<<<16,    256, 0, stream>>>(logits, attnT);
    k_ctx    <<<256,   256, 0, stream>>>(x, attnT, pctx);
    k_ctxred <<<128,   256, 0, stream>>>(pctx, ctx);
    k_x1     <<<512,   256, 0, stream>>>(Wkv, bkv, ctx, x1);
    k_h1     <<<128,   256, 0, stream>>>(Wp1, bp1, x1, h1raw);
    k_ln     <<<1,     512, 0, stream>>>(h1raw, lnw, lnb, h1);
    k_x1f    <<<512,   256, 0, stream>>>(Wp2, bp2, h1, x1f);
    k_out    <<<16384, 256, 0, stream>>>(x, x1f, out);
}

// Round 2
// 266.886 us; speedup vs baseline: 1.0201x; 1.0201x over previous
//
#include <hip/hip_runtime.h>
#include <math.h>

#define SEQ   8192
#define DIM   2048
#define NH    16
#define DH    128
#define PD    512

static constexpr float LN_EPS = 1e-5f;
static constexpr float SCALE  = 0.08838834764831845f; // 1/sqrt(128)

// ---- workspace layout (in floats) ----
static constexpr size_t OFF_QWP = 0;                        // 4*32768 split-K partials
static constexpr size_t OFF_QW  = OFF_QWP + 4*32768;        // 16*2048
static constexpr size_t OFF_QB  = OFF_QW + 32768;           // 16
static constexpr size_t OFF_MX  = OFF_QB + 16;              // 128 (16h x 8 chunks)
static constexpr size_t OFF_SM  = OFF_MX + 128;             // 128
static constexpr size_t OFF_LOG = OFF_SM + 128;             // 16*8192
static constexpr size_t OFF_ATT = OFF_LOG + 131072;         // 8192*16 transposed [s][h]
static constexpr size_t OFF_CTX = OFF_ATT + 131072;         // 16*2048
static constexpr size_t OFF_X1  = OFF_CTX + 32768;          // 2048
static constexpr size_t OFF_H1R = OFF_X1 + 2048;            // 512
static constexpr size_t OFF_H1  = OFF_H1R + 512;            // 512
static constexpr size_t OFF_X1F = OFF_H1 + 512;             // 2048
static constexpr size_t OFF_PCTX= OFF_X1F + 2048;           // nsc*16*2048 (runtime nsc)

// qW partial: split-K by 4. block = (h, jc, kc); qWp[kc][h*2048+j]
__global__ __launch_bounds__(256) void k_qw(const float* __restrict__ q,
                                            const float* __restrict__ Wkv,
                                            float* __restrict__ qWp) {
    int t = threadIdx.x;
    int kc = blockIdx.x & 3, jc = (blockIdx.x >> 2) & 7, h = blockIdx.x >> 5;
    int j = jc * 256 + t;
    const float* w  = Wkv + (size_t)(h * DH + kc * 32) * DIM + j;
    const float* qh = q + h * DH + kc * 32;
    float acc = 0.f;
#pragma unroll
    for (int d = 0; d < 32; ++d)
        acc += qh[d] * w[(size_t)d * DIM];
    qWp[(size_t)kc * 32768 + h * DIM + j] = acc;
}

__global__ __launch_bounds__(256) void k_qwred(const float* __restrict__ qWp,
                                               float* __restrict__ qW) {
    int idx = blockIdx.x * 256 + threadIdx.x;
    qW[idx] = qWp[idx] + qWp[32768 + idx] + qWp[2*32768 + idx] + qWp[3*32768 + idx];
}

// qb[h] = sum_d q[h*128+d]*b_kv[h*128+d]
__global__ void k_qb(const float* __restrict__ q, const float* __restrict__ bkv,
                     float* __restrict__ qb) {
    int h = blockIdx.x, t = threadIdx.x;
    float p = q[h*DH + t] * bkv[h*DH + t] + q[h*DH + 64 + t] * bkv[h*DH + 64 + t];
    for (int off = 32; off; off >>= 1) p += __shfl_down(p, off);
    if (t == 0) qb[h] = p;
}

// logits[h][s] = (x[s]·qW[h] + qb[h]) * SCALE
// grid (2, 512): blockIdx.x = head group (8 heads), blockIdx.y = 16-row block.
// Thread t owns cols [t*8, t*8+8). Barrier-free per-row wave fold; 1 barrier/block.
__global__ __launch_bounds__(256) void k_logits(const float* __restrict__ x,
                                                const float* __restrict__ qW,
                                                const float* __restrict__ qb,
                                                float* __restrict__ logits) {
    const int t = threadIdx.x, g = blockIdx.x;
    const int s0 = blockIdx.y * 16;
    const int j0 = t * 8;
    float4 qw0[8], qw1[8];
#pragma unroll
    for (int hh = 0; hh < 8; ++hh) {
        const float* base = qW + (size_t)(g * 8 + hh) * DIM + j0;
        qw0[hh] = *(const float4*)base;
        qw1[hh] = *(const float4*)(base + 4);
    }
    __shared__ float part[4][16][8];
    const int lane = t & 63, w = t >> 6;
    // bit-reversed 3-bit head slot for the fold-reduce
    const int head = ((lane & 1) << 2) | (lane & 2) | ((lane >> 2) & 1);
    for (int r = 0; r < 16; ++r) {
        const float* xr = x + (size_t)(s0 + r) * DIM + j0;
        float4 xa = *(const float4*)xr;
        float4 xb = *(const float4*)(xr + 4);
        float p[8];
#pragma unroll
        for (int hh = 0; hh < 8; ++hh) {
            p[hh] = xa.x*qw0[hh].x + xa.y*qw0[hh].y + xa.z*qw0[hh].z + xa.w*qw0[hh].w
                  + xb.x*qw1[hh].x + xb.y*qw1[hh].y + xb.z*qw1[hh].z + xb.w*qw1[hh].w;
        }
        // fold 8 values -> 1 per lane over xor masks 1,2,4
#pragma unroll
        for (int k = 0; k < 3; ++k) {
            const int m = 1 << k, n = 8 >> k;
            const bool hi = (lane >> k) & 1;
#pragma unroll
            for (int i = 0; i < (n >> 1); ++i) {
                float a = p[i], b = p[i + (n >> 1)];
                float send = hi ? a : b;
                float recv = __shfl_xor(send, m);
                p[i] = (hi ? b : a) + recv;
            }
        }
        float v = p[0];
        v += __shfl_xor(v, 8);
        v += __shfl_xor(v, 16);
        v += __shfl_xor(v, 32);
        if (lane < 8) part[w][r][head] = v;
    }
    __syncthreads();
    if (t < 128) {
        int r = t >> 3, hh = t & 7, h = g * 8 + hh;
        float sum = part[0][r][hh] + part[1][r][hh] + part[2][r][hh] + part[3][r][hh];
        logits[(size_t)h * SEQ + s0 + r] = (sum + qb[h]) * SCALE;
    }
}

// softmax stage 1: per (head, 1024-chunk) max + sumexp
__global__ __launch_bounds__(256) void k_smax1(const float* __restrict__ logits,
                                               float* __restrict__ mx,
                                               float* __restrict__ sm) {
    int h = blockIdx.x >> 3, c = blockIdx.x & 7, t = threadIdx.x;
    const float* l = logits + (size_t)h * SEQ + c * 1024;
    float e0 = l[t], e1 = l[256 + t], e2 = l[512 + t], e3 = l[768 + t];
    float m = fmaxf(fmaxf(e0, e1), fmaxf(e2, e3));
    for (int off = 32; off; off >>= 1) m = fmaxf(m, __shfl_xor(m, off));
    __shared__ float red[4];
    if ((t & 63) == 0) red[t >> 6] = m;
    __syncthreads();
    m = fmaxf(fmaxf(red[0], red[1]), fmaxf(red[2], red[3]));
    float s = __expf(e0 - m) + __expf(e1 - m) + __expf(e2 - m) + __expf(e3 - m);
    for (int off = 32; off; off >>= 1) s += __shfl_xor(s, off);
    __syncthreads();
    if ((t & 63) == 0) red[t >> 6] = s;
    __syncthreads();
    if (t == 0) { mx[blockIdx.x] = m; sm[blockIdx.x] = red[0] + red[1] + red[2] + red[3]; }
}

// softmax stage 2: merge chunk stats, write attnT[s][h]
__global__ __launch_bounds__(256) void k_smax2(const float* __restrict__ logits,
                                               const float* __restrict__ mx,
                                               const float* __restrict__ sm,
                                               float* __restrict__ attnT) {
    int h = blockIdx.x >> 4, c = blockIdx.x & 15, t = threadIdx.x;
    float M = -1e30f;
#pragma unroll
    for (int i = 0; i < 8; ++i) M = fmaxf(M, mx[h * 8 + i]);
    float S = 0.f;
#pragma unroll
    for (int i = 0; i < 8; ++i) S += sm[h * 8 + i] * __expf(mx[h * 8 + i] - M);
    float inv = 1.0f / S;
    const float* l = logits + (size_t)h * SEQ + c * 512;
    int s0 = c * 512;
    attnT[(size_t)(s0 + t) * NH + h]       = __expf(l[t] - M) * inv;
    attnT[(size_t)(s0 + 256 + t) * NH + h] = __expf(l[256 + t] - M) * inv;
}

// partial ctx: pctx[sc][h][j..j+4) = sum_{s in chunk} attnT[s][h] * x[s][j..j+4)
// grid 2*nsc: jc = bx&1 (1024-col half), sc = bx>>1 (R rows each)
__global__ __launch_bounds__(256) void k_ctx(const float* __restrict__ x,
                                             const float* __restrict__ attnT,
                                             float* __restrict__ pctx, int R) {
    int jc = blockIdx.x & 1, sc = blockIdx.x >> 1, t = threadIdx.x;
    int j = jc * 1024 + t * 4;
    float4 acc[NH];
#pragma unroll
    for (int h = 0; h < NH; ++h) acc[h] = make_float4(0.f, 0.f, 0.f, 0.f);
    int s0 = sc * R;
    for (int r = 0; r < R; ++r) {
        int s = s0 + r;
        float4 xv = *(const float4*)&x[(size_t)s * DIM + j];
        const float4* ap = (const float4*)(attnT + (size_t)s * NH);
        float4 a0 = ap[0], a1 = ap[1], a2 = ap[2], a3 = ap[3];
        float aa[16];
        *(float4*)&aa[0]  = a0; *(float4*)&aa[4]  = a1;
        *(float4*)&aa[8]  = a2; *(float4*)&aa[12] = a3;
#pragma unroll
        for (int h = 0; h < NH; ++h) {
            acc[h].x += aa[h] * xv.x;
            acc[h].y += aa[h] * xv.y;
            acc[h].z += aa[h] * xv.z;
            acc[h].w += aa[h] * xv.w;
        }
    }
#pragma unroll
    for (int h = 0; h < NH; ++h)
        *(float4*)&pctx[((size_t)(sc * NH + h)) * DIM + j] = acc[h];
}

// ctx[h][j] = sum_sc pctx[sc][h][j]
__global__ __launch_bounds__(256) void k_ctxred(const float* __restrict__ pctx,
                                                float* __restrict__ ctx, int nsc) {
    int idx = blockIdx.x * 256 + threadIdx.x; // 0..32767
    float s = 0.f;
    for (int sc = 0; sc < nsc; ++sc)
        s += pctx[(size_t)sc * (NH * DIM) + idx];
    ctx[idx] = s;
}

// x1[row] = ctx[row>>7]·W_v[row] + b_kv[DIM+row]; one wave per row
__global__ __launch_bounds__(256) void k_x1(const float* __restrict__ Wkv,
                                            const float* __restrict__ bkv,
                                            const float* __restrict__ ctx,
                                            float* __restrict__ x1) {
    int row = blockIdx.x * 4 + (threadIdx.x >> 6);
    int lane = threadIdx.x & 63;
    const float* w = Wkv + (size_t)(DIM + row) * DIM;
    const float* c = ctx + (row >> 7) * DIM;
    float acc = 0.f;
#pragma unroll
    for (int k = 0; k < 8; ++k) {
        int j = k * 256 + lane * 4;
        float4 wv = *(const float4*)&w[j];
        float4 cv = *(const float4*)&c[j];
        acc += wv.x*cv.x + wv.y*cv.y + wv.z*cv.z + wv.w*cv.w;
    }
    for (int off = 32; off; off >>= 1) acc += __shfl_xor(acc, off);
    if (lane == 0) x1[row] = acc + bkv[DIM + row];
}

// h1raw[row] = x1·W_p1[row] + b_p1[row]
__global__ __launch_bounds__(256) void k_h1(const float* __restrict__ Wp1,
                                            const float* __restrict__ bp1,
                                            const float* __restrict__ x1,
                                            float* __restrict__ h1raw) {
    int row = blockIdx.x * 4 + (threadIdx.x >> 6);
    int lane = threadIdx.x & 63;
    const float* w = Wp1 + (size_t)row * DIM;
    float acc = 0.f;
#pragma unroll
    for (int k = 0; k < 8; ++k) {
        int j = k * 256 + lane * 4;
        float4 wv = *(const float4*)&w[j];
        float4 cv = *(const float4*)&x1[j];
        acc += wv.x*cv.x + wv.y*cv.y + wv.z*cv.z + wv.w*cv.w;
    }
    for (int off = 32; off; off >>= 1) acc += __shfl_xor(acc, off);
    if (lane == 0) h1raw[row] = acc + bp1[row];
}

// LayerNorm + relu over 512 elems; single block of 512
__global__ __launch_bounds__(512) void k_ln(const float* __restrict__ h1raw,
                                            const float* __restrict__ lnw,
                                            const float* __restrict__ lnb,
                                            float* __restrict__ h1) {
    int t = threadIdx.x;
    __shared__ float red[8];
    float v = h1raw[t];
    float s = v;
    for (int off = 32; off; off >>= 1) s += __shfl_xor(s, off);
    if ((t & 63) == 0) red[t >> 6] = s;
    __syncthreads();
    float mu = 0.f;
#pragma unroll
    for (int i = 0; i < 8; ++i) mu += red[i];
    mu *= (1.0f / PD);
    float d = v - mu;
    float s2 = d * d;
    for (int off = 32; off; off >>= 1) s2 += __shfl_xor(s2, off);
    __syncthreads();
    if ((t & 63) == 0) red[t >> 6] = s2;
    __syncthreads();
    float var = 0.f;
#pragma unroll
    for (int i = 0; i < 8; ++i) var += red[i];
    var *= (1.0f / PD);
    float y = d * rsqrtf(var + LN_EPS) * lnw[t] + lnb[t];
    h1[t] = fmaxf(y, 0.f);
}

// x1f[row] = relu(h1)·W_p2[row] + b_p2[row]
__global__ __launch_bounds__(256) void k_x1f(const float* __restrict__ Wp2,
                                             const float* __restrict__ bp2,
                                             const float* __restrict__ h1,
                                             float* __restrict__ x1f) {
    int row = blockIdx.x * 4 + (threadIdx.x >> 6);
    int lane = threadIdx.x & 63;
    const float* w = Wp2 + (size_t)row * PD;
    float acc = 0.f;
#pragma unroll
    for (int k = 0; k < 2; ++k) {
        int j = k * 256 + lane * 4;
        float4 wv = *(const float4*)&w[j];
        float4 cv = *(const float4*)&h1[j];
        acc += wv.x*cv.x + wv.y*cv.y + wv.z*cv.z + wv.w*cv.w;
    }
    for (int off = 32; off; off >>= 1) acc += __shfl_xor(acc, off);
    if (lane == 0) x1f[row] = acc + bp2[row];
}

// out[s][j] = x[s][j] + x1f[j]; 2 float4 per thread
__global__ __launch_bounds__(256) void k_out(const float* __restrict__ x,
                                             const float* __restrict__ x1f,
                                             float* __restrict__ out) {
    size_t i = (size_t)blockIdx.x * 512 + threadIdx.x;
    float4 xv = ((const float4*)x)[i];
    float4 a  = ((const float4*)x1f)[(int)(i & 511)];
    ((float4*)out)[i] = make_float4(xv.x + a.x, xv.y + a.y, xv.z + a.z, xv.w + a.w);
    size_t i2 = i + 256;
    float4 xv2 = ((const float4*)x)[i2];
    float4 a2  = ((const float4*)x1f)[(int)(i2 & 511)];
    ((float4*)out)[i2] = make_float4(xv2.x + a2.x, xv2.y + a2.y, xv2.z + a2.z, xv2.w + a2.w);
}

extern "C" void kernel_launch(void* const* d_in, const int* in_sizes, int n_in,
                              void* d_out, int out_size, void* d_ws, size_t ws_size,
                              hipStream_t stream) {
    const float* x    = (const float*)d_in[0];
    const float* q    = (const float*)d_in[1];
    const float* Wkv  = (const float*)d_in[2];
    const float* bkv  = (const float*)d_in[3];
    const float* Wp1  = (const float*)d_in[4];
    const float* bp1  = (const float*)d_in[5];
    const float* Wp2  = (const float*)d_in[6];
    const float* bp2  = (const float*)d_in[7];
    const float* lnw  = (const float*)d_in[8];
    const float* lnb  = (const float*)d_in[9];
    float* out = (float*)d_out;
    float* ws  = (float*)d_ws;

    float* qWp   = ws + OFF_QWP;
    float* qW    = ws + OFF_QW;
    float* qb    = ws + OFF_QB;
    float* mx    = ws + OFF_MX;
    float* sm    = ws + OFF_SM;
    float* logits= ws + OFF_LOG;
    float* attnT = ws + OFF_ATT;
    float* ctx   = ws + OFF_CTX;
    float* x1    = ws + OFF_X1;
    float* h1raw = ws + OFF_H1R;
    float* h1    = ws + OFF_H1;
    float* x1f   = ws + OFF_X1F;
    float* pctx  = ws + OFF_PCTX;

    // pctx chunk count: 128 if workspace allows (19 MB), else 32 (6 MB, known-safe)
    int nsc = (ws_size >= (OFF_PCTX + (size_t)128 * NH * DIM) * sizeof(float)) ? 128 : 32;
    int R = SEQ / nsc;

    k_qw    <<<512, 256, 0, stream>>>(q, Wkv, qWp);
    k_qwred <<<128, 256, 0, stream>>>(qWp, qW);
    k_qb    <<<16,   64, 0, stream>>>(q, bkv, qb);
    k_logits<<<dim3(2, 512), 256, 0, stream>>>(x, qW, qb, logits);
    k_smax1 <<<128, 256, 0, stream>>>(logits, mx, sm);
    k_smax2 <<<256, 256, 0, stream>>>(logits, mx, sm, attnT);
    k_ctx   <<<2 * nsc, 256, 0, stream>>>(x, attnT, pctx, R);
    k_ctxred<<<128, 256, 0, stream>>>(pctx, ctx, nsc);
    k_x1    <<<512, 256, 0, stream>>>(Wkv, bkv, ctx, x1);
    k_h1    <<<128, 256, 0, stream>>>(Wp1, bp1, x1, h1raw);
    k_ln    <<<1,   512, 0, stream>>>(h1raw, lnw, lnb, h1);
    k_x1f   <<<512, 256, 0, stream>>>(Wp2, bp2, h1, x1f);
    k_out   <<<8192, 256, 0, stream>>>(x, x1f, out);
}

// Round 3
// 244.455 us; speedup vs baseline: 1.1137x; 1.0918x over previous
//
#include <hip/hip_runtime.h>
#include <math.h>

#define SEQ   8192
#define DIM   2048
#define NH    16
#define DH    128
#define PD    512

static constexpr float LN_EPS = 1e-5f;
static constexpr float SCALE  = 0.08838834764831845f; // 1/sqrt(128)

// ---- workspace layout (in floats); all offsets divisible by 4 (16B aligned) ----
static constexpr size_t OFF_QW   = 0;                        // 16*2048
static constexpr size_t OFF_QB   = OFF_QW + 32768;           // 16
static constexpr size_t OFF_SMP  = OFF_QB + 16;              // 128 = smp[h][8] exp-sum partials
static constexpr size_t OFF_ELOG = OFF_SMP + 128;            // 16*8192 exp(logit)
static constexpr size_t OFF_PCTX = OFF_ELOG + 131072;        // 64*16*2048
static constexpr size_t OFF_CTX  = OFF_PCTX + 64*32768;      // 16*2048
static constexpr size_t OFF_X1   = OFF_CTX + 32768;          // 2048
static constexpr size_t OFF_H1R  = OFF_X1 + 2048;            // 512
static constexpr size_t OFF_X1F  = OFF_H1R + 512;            // 2048

// qW[h][j] = sum_d q[h*128+d]*W_kv[(h*128+d)*DIM+j]; also qb[h]; also zeroes smp.
// grid 256 = (h 16) x (jc 16); 256 thr: col = t&127, k-half = t>>7 (64 d each)
__global__ __launch_bounds__(256) void k_prep(const float* __restrict__ q,
                                              const float* __restrict__ Wkv,
                                              const float* __restrict__ bkv,
                                              float* __restrict__ qW,
                                              float* __restrict__ qb,
                                              float* __restrict__ smp) {
    int t = threadIdx.x;
    int h = blockIdx.x >> 4, jc = blockIdx.x & 15;
    int col = t & 127, kh = t >> 7;
    int j = jc * 128 + col;
    const float* w  = Wkv + (size_t)(h * DH + kh * 64) * DIM + j;
    const float* qh = q + h * DH + kh * 64;
    float acc = 0.f;
#pragma unroll 16
    for (int d = 0; d < 64; ++d)
        acc += qh[d] * w[(size_t)d * DIM];
    __shared__ float part[128];
    if (kh) part[col] = acc;
    __syncthreads();
    if (!kh) qW[h * DIM + j] = acc + part[col];
    if (jc == 0 && t < 64) {
        float p = q[h*DH + t] * bkv[h*DH + t] + q[h*DH + 64 + t] * bkv[h*DH + 64 + t];
        for (int off = 32; off; off >>= 1) p += __shfl_down(p, off);
        if (t == 0) qb[h] = p;
    }
    if (blockIdx.x == 0 && t < 128) smp[t] = 0.f;  // runs before k_logits (stream order)
}

// elog[h][s] = exp((x[s]·qW[h] + qb[h])*SCALE); atomic partial exp-sums into smp.
// grid (2, 512): g = 8-head group, y = 16-row block. Thread t owns cols [t*8,t*8+8).
__global__ __launch_bounds__(256) void k_logits(const float* __restrict__ x,
                                                const float* __restrict__ qW,
                                                const float* __restrict__ qb,
                                                float* __restrict__ elog,
                                                float* __restrict__ smp) {
    const int t = threadIdx.x, g = blockIdx.x;
    const int s0 = blockIdx.y * 16;
    const int j0 = t * 8;
    float4 qw0[8], qw1[8];
#pragma unroll
    for (int hh = 0; hh < 8; ++hh) {
        const float* base = qW + (size_t)(g * 8 + hh) * DIM + j0;
        qw0[hh] = *(const float4*)base;
        qw1[hh] = *(const float4*)(base + 4);
    }
    __shared__ float part[4][16][8];
    __shared__ float esh[16][8];
    const int lane = t & 63, w = t >> 6;
    const int head = ((lane & 1) << 2) | (lane & 2) | ((lane >> 2) & 1); // bit-rev 3b
    for (int r = 0; r < 16; ++r) {
        const float* xr = x + (size_t)(s0 + r) * DIM + j0;
        float4 xa = *(const float4*)xr;
        float4 xb = *(const float4*)(xr + 4);
        float p[8];
#pragma unroll
        for (int hh = 0; hh < 8; ++hh) {
            p[hh] = xa.x*qw0[hh].x + xa.y*qw0[hh].y + xa.z*qw0[hh].z + xa.w*qw0[hh].w
                  + xb.x*qw1[hh].x + xb.y*qw1[hh].y + xb.z*qw1[hh].z + xb.w*qw1[hh].w;
        }
#pragma unroll
        for (int k = 0; k < 3; ++k) {
            const int m = 1 << k, n = 8 >> k;
            const bool hi = (lane >> k) & 1;
#pragma unroll
            for (int i = 0; i < (n >> 1); ++i) {
                float a = p[i], b = p[i + (n >> 1)];
                float send = hi ? a : b;
                float recv = __shfl_xor(send, m);
                p[i] = (hi ? b : a) + recv;
            }
        }
        float v = p[0];
        v += __shfl_xor(v, 8);
        v += __shfl_xor(v, 16);
        v += __shfl_xor(v, 32);
        if (lane < 8) part[w][r][head] = v;
    }
    __syncthreads();
    if (t < 128) {
        int r = t >> 3, hh = t & 7, h = g * 8 + hh;
        float sum = part[0][r][hh] + part[1][r][hh] + part[2][r][hh] + part[3][r][hh];
        float e = __expf((sum + qb[h]) * SCALE);   // no max-sub: |logit| <~ 5
        elog[(size_t)h * SEQ + s0 + r] = e;
        esh[r][hh] = e;
    }
    __syncthreads();
    if (t < 8) {
        float s = 0.f;
#pragma unroll
        for (int r = 0; r < 16; ++r) s += esh[r][t];
        atomicAdd(&smp[(g * 8 + t) * 8 + (blockIdx.y & 7)], s);
    }
}

// pctx[sc][h][j..j+2) = sum_{s in chunk sc} (elog[h][s]/S[h]) * x[s][j..j+2)
// grid 256 = (sc 0..63) x (jc 0..3); R=128 rows, 512 cols (float2/thread)
__global__ __launch_bounds__(256) void k_ctx(const float* __restrict__ x,
                                             const float* __restrict__ elog,
                                             const float* __restrict__ smp,
                                             float* __restrict__ pctx) {
    int jc = blockIdx.x & 3, sc = blockIdx.x >> 2, t = threadIdx.x;
    int s0 = sc * 128;
    int j = jc * 512 + t * 2;
    __shared__ float inv_s[NH];
    __shared__ float att[128][NH];
    if (t < NH) {
        float S = 0.f;
#pragma unroll
        for (int i = 0; i < 8; ++i) S += smp[t * 8 + i];
        inv_s[t] = 1.0f / S;
    }
    __syncthreads();
    for (int i = t; i < 128 * NH; i += 256) {
        int h = i >> 7, r = i & 127;
        att[r][h] = elog[(size_t)h * SEQ + s0 + r] * inv_s[h];
    }
    __syncthreads();
    float2 acc[NH];
#pragma unroll
    for (int h = 0; h < NH; ++h) acc[h] = make_float2(0.f, 0.f);
    for (int r = 0; r < 128; ++r) {
        float2 xv = *(const float2*)&x[(size_t)(s0 + r) * DIM + j];
        const float4* ar = (const float4*)att[r];   // broadcast LDS reads
        float4 a0 = ar[0], a1 = ar[1], a2 = ar[2], a3 = ar[3];
        float aa[NH];
        *(float4*)&aa[0] = a0; *(float4*)&aa[4]  = a1;
        *(float4*)&aa[8] = a2; *(float4*)&aa[12] = a3;
#pragma unroll
        for (int h = 0; h < NH; ++h) {
            acc[h].x += aa[h] * xv.x;
            acc[h].y += aa[h] * xv.y;
        }
    }
#pragma unroll
    for (int h = 0; h < NH; ++h)
        *(float2*)&pctx[((size_t)(sc * NH + h)) * DIM + j] = acc[h];
}

// ctx[idx] = sum_{sc<64} pctx[sc][idx]
__global__ __launch_bounds__(256) void k_ctxred(const float* __restrict__ pctx,
                                                float* __restrict__ ctx) {
    int idx = blockIdx.x * 256 + threadIdx.x; // 0..32767
    float s = 0.f;
#pragma unroll 8
    for (int sc = 0; sc < 64; ++sc)
        s += pctx[(size_t)sc * (NH * DIM) + idx];
    ctx[idx] = s;
}

// x1[row] = ctx[row>>7]·W_v[row] + b_kv[DIM+row]; one wave/row, 4 rows/block
__global__ __launch_bounds__(256) void k_x1(const float* __restrict__ Wkv,
                                            const float* __restrict__ bkv,
                                            const float* __restrict__ ctx,
                                            float* __restrict__ x1) {
    int row = blockIdx.x * 4 + (threadIdx.x >> 6);
    int lane = threadIdx.x & 63;
    const float* w = Wkv + (size_t)(DIM + row) * DIM;
    const float* c = ctx + (row >> 7) * DIM;
    float acc = 0.f;
#pragma unroll
    for (int k = 0; k < 8; ++k) {
        int j = k * 256 + lane * 4;
        float4 wv = *(const float4*)&w[j];
        float4 cv = *(const float4*)&c[j];
        acc += wv.x*cv.x + wv.y*cv.y + wv.z*cv.z + wv.w*cv.w;
    }
    for (int off = 32; off; off >>= 1) acc += __shfl_xor(acc, off);
    if (lane == 0) x1[row] = acc + bkv[DIM + row];
}

// h1raw[row] = x1·W_p1[row] + b_p1[row]
__global__ __launch_bounds__(256) void k_h1(const float* __restrict__ Wp1,
                                            const float* __restrict__ bp1,
                                            const float* __restrict__ x1,
                                            float* __restrict__ h1raw) {
    int row = blockIdx.x * 4 + (threadIdx.x >> 6);
    int lane = threadIdx.x & 63;
    const float* w = Wp1 + (size_t)row * DIM;
    float acc = 0.f;
#pragma unroll
    for (int k = 0; k < 8; ++k) {
        int j = k * 256 + lane * 4;
        float4 wv = *(const float4*)&w[j];
        float4 cv = *(const float4*)&x1[j];
        acc += wv.x*cv.x + wv.y*cv.y + wv.z*cv.z + wv.w*cv.w;
    }
    for (int off = 32; off; off >>= 1) acc += __shfl_xor(acc, off);
    if (lane == 0) h1raw[row] = acc + bp1[row];
}

// Fused LN+relu+proj2: x1f[row] = relu(LN(h1raw))·W_p2[row] + b_p2[row]
// One wave/row; each wave recomputes LN stats from registers (no barriers).
__global__ __launch_bounds__(256) void k_x1f(const float* __restrict__ Wp2,
                                             const float* __restrict__ bp2,
                                             const float* __restrict__ h1raw,
                                             const float* __restrict__ lnw,
                                             const float* __restrict__ lnb,
                                             float* __restrict__ x1f) {
    int row = blockIdx.x * 4 + (threadIdx.x >> 6);
    int lane = threadIdx.x & 63;
    int j = lane * 8;
    float4 va = *(const float4*)&h1raw[j];
    float4 vb = *(const float4*)&h1raw[j + 4];
    float s = va.x + va.y + va.z + va.w + vb.x + vb.y + vb.z + vb.w;
    for (int off = 32; off; off >>= 1) s += __shfl_xor(s, off);
    float mu = s * (1.0f / PD);
    float dx[8];
    dx[0]=va.x-mu; dx[1]=va.y-mu; dx[2]=va.z-mu; dx[3]=va.w-mu;
    dx[4]=vb.x-mu; dx[5]=vb.y-mu; dx[6]=vb.z-mu; dx[7]=vb.w-mu;
    float s2 = 0.f;
#pragma unroll
    for (int i = 0; i < 8; ++i) s2 += dx[i] * dx[i];
    for (int off = 32; off; off >>= 1) s2 += __shfl_xor(s2, off);
    float rstd = rsqrtf(s2 * (1.0f / PD) + LN_EPS);
    float4 lw0 = *(const float4*)&lnw[j], lw1 = *(const float4*)&lnw[j + 4];
    float4 lb0 = *(const float4*)&lnb[j], lb1 = *(const float4*)&lnb[j + 4];
    float hln[8];
    hln[0]=fmaxf(dx[0]*rstd*lw0.x+lb0.x,0.f); hln[1]=fmaxf(dx[1]*rstd*lw0.y+lb0.y,0.f);
    hln[2]=fmaxf(dx[2]*rstd*lw0.z+lb0.z,0.f); hln[3]=fmaxf(dx[3]*rstd*lw0.w+lb0.w,0.f);
    hln[4]=fmaxf(dx[4]*rstd*lw1.x+lb1.x,0.f); hln[5]=fmaxf(dx[5]*rstd*lw1.y+lb1.y,0.f);
    hln[6]=fmaxf(dx[6]*rstd*lw1.z+lb1.z,0.f); hln[7]=fmaxf(dx[7]*rstd*lw1.w+lb1.w,0.f);
    const float* w = Wp2 + (size_t)row * PD + j;
    float4 w0 = *(const float4*)w, w1 = *(const float4*)(w + 4);
    float acc = w0.x*hln[0] + w0.y*hln[1] + w0.z*hln[2] + w0.w*hln[3]
              + w1.x*hln[4] + w1.y*hln[5] + w1.z*hln[6] + w1.w*hln[7];
    for (int off = 32; off; off >>= 1) acc += __shfl_xor(acc, off);
    if (lane == 0) x1f[row] = acc + bp2[row];
}

// out[s][j] = x[s][j] + x1f[j]; 2 float4/thread
__global__ __launch_bounds__(256) void k_out(const float* __restrict__ x,
                                             const float* __restrict__ x1f,
                                             float* __restrict__ out) {
    size_t i = (size_t)blockIdx.x * 512 + threadIdx.x;
    float4 xv = ((const float4*)x)[i];
    float4 a  = ((const float4*)x1f)[(int)(i & 511)];
    ((float4*)out)[i] = make_float4(xv.x + a.x, xv.y + a.y, xv.z + a.z, xv.w + a.w);
    size_t i2 = i + 256;
    float4 xv2 = ((const float4*)x)[i2];
    float4 a2  = ((const float4*)x1f)[(int)(i2 & 511)];
    ((float4*)out)[i2] = make_float4(xv2.x + a2.x, xv2.y + a2.y, xv2.z + a2.z, xv2.w + a2.w);
}

extern "C" void kernel_launch(void* const* d_in, const int* in_sizes, int n_in,
                              void* d_out, int out_size, void* d_ws, size_t ws_size,
                              hipStream_t stream) {
    const float* x    = (const float*)d_in[0];
    const float* q    = (const float*)d_in[1];
    const float* Wkv  = (const float*)d_in[2];
    const float* bkv  = (const float*)d_in[3];
    const float* Wp1  = (const float*)d_in[4];
    const float* bp1  = (const float*)d_in[5];
    const float* Wp2  = (const float*)d_in[6];
    const float* bp2  = (const float*)d_in[7];
    const float* lnw  = (const float*)d_in[8];
    const float* lnb  = (const float*)d_in[9];
    float* out = (float*)d_out;
    float* ws  = (float*)d_ws;

    float* qW    = ws + OFF_QW;
    float* qb    = ws + OFF_QB;
    float* smp   = ws + OFF_SMP;
    float* elog  = ws + OFF_ELOG;
    float* pctx  = ws + OFF_PCTX;
    float* ctx   = ws + OFF_CTX;
    float* x1    = ws + OFF_X1;
    float* h1raw = ws + OFF_H1R;
    float* x1f   = ws + OFF_X1F;

    k_prep  <<<256, 256, 0, stream>>>(q, Wkv, bkv, qW, qb, smp);
    k_logits<<<dim3(2, 512), 256, 0, stream>>>(x, qW, qb, elog, smp);
    k_ctx   <<<256, 256, 0, stream>>>(x, elog, smp, pctx);
    k_ctxred<<<128, 256, 0, stream>>>(pctx, ctx);
    k_x1    <<<512, 256, 0, stream>>>(Wkv, bkv, ctx, x1);
    k_h1    <<<128, 256, 0, stream>>>(Wp1, bp1, x1, h1raw);
    k_x1f   <<<512, 256, 0, stream>>>(Wp2, bp2, h1raw, lnw, lnb, x1f);
    k_out   <<<8192, 256, 0, stream>>>(x, x1f, out);
}

// Round 4
// 222.242 us; speedup vs baseline: 1.2250x; 1.1000x over previous
//
#include <hip/hip_runtime.h>
#include <math.h>

#define SEQ   8192
#define DIM   2048
#define NH    16
#define DH    128
#define PD    512

static constexpr float LN_EPS = 1e-5f;
static constexpr float SCALE  = 0.08838834764831845f; // 1/sqrt(128)

typedef __bf16 bf16x8 __attribute__((ext_vector_type(8)));
typedef float  f32x4  __attribute__((ext_vector_type(4)));

// ---- workspace layout (in floats); all offsets multiple of 4 (16B aligned) ----
static constexpr size_t OFF_QB   = 0;                         // 16
static constexpr size_t OFF_SMP  = 16;                        // 512 = smp[h][32] exp-sum partials
static constexpr size_t OFF_QWB  = 528;                       // 16*2048 bf16 = 16384 floats
static constexpr size_t OFF_ELOG = OFF_QWB + 16384;           // 8192*16 exp(logit), [s][h]
static constexpr size_t OFF_PCTX = OFF_ELOG + 131072;         // 128*16*2048
static constexpr size_t OFF_CTX  = OFF_PCTX + 128*32768;      // 16*2048
static constexpr size_t OFF_X1   = OFF_CTX + 32768;           // 2048
static constexpr size_t OFF_H1R  = OFF_X1 + 2048;             // 512
static constexpr size_t OFF_X1F  = OFF_H1R + 512;             // 2048

// qWb[h][j] = bf16( sum_d q[h*128+d]*W_kv[(h*128+d)*DIM+j] ); qb[h]; zero smp.
// grid 256 = (h 16) x (jc 16); 256 thr: col = t&127, k-half = t>>7
__global__ __launch_bounds__(256) void k_prep(const float* __restrict__ q,
                                              const float* __restrict__ Wkv,
                                              const float* __restrict__ bkv,
                                              __bf16* __restrict__ qWb,
                                              float* __restrict__ qb,
                                              float* __restrict__ smp) {
    int t = threadIdx.x;
    int h = blockIdx.x >> 4, jc = blockIdx.x & 15;
    int col = t & 127, kh = t >> 7;
    int j = jc * 128 + col;
    const float* w  = Wkv + (size_t)(h * DH + kh * 64) * DIM + j;
    const float* qh = q + h * DH + kh * 64;
    float acc = 0.f;
#pragma unroll 16
    for (int d = 0; d < 64; ++d)
        acc += qh[d] * w[(size_t)d * DIM];
    __shared__ float part[128];
    if (kh) part[col] = acc;
    __syncthreads();
    if (!kh) qWb[h * DIM + j] = (__bf16)(acc + part[col]);
    if (jc == 0 && t < 64) {
        float p = q[h*DH + t] * bkv[h*DH + t] + q[h*DH + 64 + t] * bkv[h*DH + 64 + t];
        for (int off = 32; off; off >>= 1) p += __shfl_down(p, off);
        if (t == 0) qb[h] = p;
    }
    if (blockIdx.x == 0) { smp[t] = 0.f; smp[t + 256] = 0.f; }
}

// MFMA logits: elogT[s][h] = exp((x[s]·qW[h] + qb[h])*SCALE), partial sums -> smp.
// grid 512 (16 s-rows each), 256 thr = 4 waves, wave w = K-quarter w (512 k, 16 MFMA).
// A = x rows (fp32->bf16 otf), B = qWb. D[s=quad*4+reg][h=lane&15].
__global__ __launch_bounds__(256) void k_logits(const float* __restrict__ x,
                                                const __bf16* __restrict__ qWb,
                                                const float* __restrict__ qb,
                                                float* __restrict__ elogT,
                                                float* __restrict__ smp) {
    const int t = threadIdx.x;
    const int w = t >> 6, lane = t & 63;
    const int r = lane & 15, quad = lane >> 4;
    const int s0 = blockIdx.x * 16;
    __shared__ float dpart[4][64][4];
    __shared__ float hsum[NH];
    if (t < NH) hsum[t] = 0.f;

    const float*  xrow = x + (size_t)(s0 + r) * DIM + quad * 8;
    const __bf16* brow = qWb + r * DIM + quad * 8;  // r doubles as h for B operand
    const int kbase = w * 512;

    f32x4 acc = {0.f, 0.f, 0.f, 0.f};
#pragma unroll 4
    for (int i = 0; i < 16; ++i) {
        int k = kbase + i * 32;
        float4 xa = *(const float4*)(xrow + k);
        float4 xb = *(const float4*)(xrow + k + 4);
        bf16x8 af;
        af[0] = (__bf16)xa.x; af[1] = (__bf16)xa.y;
        af[2] = (__bf16)xa.z; af[3] = (__bf16)xa.w;
        af[4] = (__bf16)xb.x; af[5] = (__bf16)xb.y;
        af[6] = (__bf16)xb.z; af[7] = (__bf16)xb.w;
        bf16x8 bf = *(const bf16x8*)(brow + k);
        acc = __builtin_amdgcn_mfma_f32_16x16x32_bf16(af, bf, acc, 0, 0, 0);
    }
    dpart[w][lane][0] = acc[0];
    dpart[w][lane][1] = acc[1];
    dpart[w][lane][2] = acc[2];
    dpart[w][lane][3] = acc[3];
    __syncthreads();

    {   // t -> (lane2 = t&63, reg = t>>6); s_local = (lane2>>4)*4+reg, h = lane2&15
        const int lane2 = t & 63, reg = t >> 6;
        const int h = lane2 & 15, sl = (lane2 >> 4) * 4 + reg;
        float v = dpart[0][lane2][reg] + dpart[1][lane2][reg]
                + dpart[2][lane2][reg] + dpart[3][lane2][reg];
        float e = __expf((v + qb[h]) * SCALE);   // no max-sub: |logit| <~ 5
        elogT[(size_t)(s0 + sl) * NH + h] = e;
        atomicAdd(&hsum[h], e);
    }
    __syncthreads();
    if (t < NH) atomicAdd(&smp[t * 32 + (blockIdx.x & 31)], hsum[t]);
}

// pctx[sc][h][j..j+2) = sum_{s in 64-chunk} (elogT[s][h]/S[h]) * x[s][j..j+2)
// grid 512 = (sc 0..127) x (jc 0..3)
__global__ __launch_bounds__(256) void k_ctx(const float* __restrict__ x,
                                             const float* __restrict__ elogT,
                                             const float* __restrict__ smp,
                                             float* __restrict__ pctx) {
    int jc = blockIdx.x & 3, sc = blockIdx.x >> 2, t = threadIdx.x;
    int s0 = sc * 64;
    int j = jc * 512 + t * 2;
    __shared__ float inv_s[NH];
    __shared__ float att[64][NH];
    if (t < NH) {
        float S = 0.f;
#pragma unroll
        for (int i = 0; i < 32; ++i) S += smp[t * 32 + i];
        inv_s[t] = 1.0f / S;
    }
    __syncthreads();
    for (int i = t; i < 64 * NH; i += 256) {
        int rr = i >> 4, h = i & 15;
        att[rr][h] = elogT[(size_t)(s0 + rr) * NH + h] * inv_s[h];  // coalesced
    }
    __syncthreads();
    float2 acc[NH];
#pragma unroll
    for (int h = 0; h < NH; ++h) acc[h] = make_float2(0.f, 0.f);
    for (int rr = 0; rr < 64; ++rr) {
        float2 xv = *(const float2*)&x[(size_t)(s0 + rr) * DIM + j];
        const float4* ar = (const float4*)att[rr];   // broadcast LDS reads
        float4 a0 = ar[0], a1 = ar[1], a2 = ar[2], a3 = ar[3];
        float aa[NH];
        *(float4*)&aa[0] = a0; *(float4*)&aa[4]  = a1;
        *(float4*)&aa[8] = a2; *(float4*)&aa[12] = a3;
#pragma unroll
        for (int h = 0; h < NH; ++h) {
            acc[h].x += aa[h] * xv.x;
            acc[h].y += aa[h] * xv.y;
        }
    }
#pragma unroll
    for (int h = 0; h < NH; ++h)
        *(float2*)&pctx[((size_t)(sc * NH + h)) * DIM + j] = acc[h];
}

// ctx[idx] = sum_{sc<128} pctx[sc][idx]
__global__ __launch_bounds__(256) void k_ctxred(const float* __restrict__ pctx,
                                                float* __restrict__ ctx) {
    int idx = blockIdx.x * 256 + threadIdx.x; // 0..32767
    float s = 0.f;
#pragma unroll 8
    for (int sc = 0; sc < 128; ++sc)
        s += pctx[(size_t)sc * (NH * DIM) + idx];
    ctx[idx] = s;
}

// x1[row] = ctx[row>>7]·W_v[row] + b_kv[DIM+row]; one wave/row, 4 rows/block
__global__ __launch_bounds__(256) void k_x1(const float* __restrict__ Wkv,
                                            const float* __restrict__ bkv,
                                            const float* __restrict__ ctx,
                                            float* __restrict__ x1) {
    int row = blockIdx.x * 4 + (threadIdx.x >> 6);
    int lane = threadIdx.x & 63;
    const float* w = Wkv + (size_t)(DIM + row) * DIM;
    const float* c = ctx + (row >> 7) * DIM;
    float acc = 0.f;
#pragma unroll
    for (int k = 0; k < 8; ++k) {
        int j = k * 256 + lane * 4;
        float4 wv = *(const float4*)&w[j];
        float4 cv = *(const float4*)&c[j];
        acc += wv.x*cv.x + wv.y*cv.y + wv.z*cv.z + wv.w*cv.w;
    }
    for (int off = 32; off; off >>= 1) acc += __shfl_xor(acc, off);
    if (lane == 0) x1[row] = acc + bkv[DIM + row];
}

// h1raw[row] = x1·W_p1[row] + b_p1[row]
__global__ __launch_bounds__(256) void k_h1(const float* __restrict__ Wp1,
                                            const float* __restrict__ bp1,
                                            const float* __restrict__ x1,
                                            float* __restrict__ h1raw) {
    int row = blockIdx.x * 4 + (threadIdx.x >> 6);
    int lane = threadIdx.x & 63;
    const float* w = Wp1 + (size_t)row * DIM;
    float acc = 0.f;
#pragma unroll
    for (int k = 0; k < 8; ++k) {
        int j = k * 256 + lane * 4;
        float4 wv = *(const float4*)&w[j];
        float4 cv = *(const float4*)&x1[j];
        acc += wv.x*cv.x + wv.y*cv.y + wv.z*cv.z + wv.w*cv.w;
    }
    for (int off = 32; off; off >>= 1) acc += __shfl_xor(acc, off);
    if (lane == 0) h1raw[row] = acc + bp1[row];
}

// Fused LN+relu+proj2: x1f[row] = relu(LN(h1raw))·W_p2[row] + b_p2[row]
__global__ __launch_bounds__(256) void k_x1f(const float* __restrict__ Wp2,
                                             const float* __restrict__ bp2,
                                             const float* __restrict__ h1raw,
                                             const float* __restrict__ lnw,
                                             const float* __restrict__ lnb,
                                             float* __restrict__ x1f) {
    int row = blockIdx.x * 4 + (threadIdx.x >> 6);
    int lane = threadIdx.x & 63;
    int j = lane * 8;
    float4 va = *(const float4*)&h1raw[j];
    float4 vb = *(const float4*)&h1raw[j + 4];
    float s = va.x + va.y + va.z + va.w + vb.x + vb.y + vb.z + vb.w;
    for (int off = 32; off; off >>= 1) s += __shfl_xor(s, off);
    float mu = s * (1.0f / PD);
    float dx[8];
    dx[0]=va.x-mu; dx[1]=va.y-mu; dx[2]=va.z-mu; dx[3]=va.w-mu;
    dx[4]=vb.x-mu; dx[5]=vb.y-mu; dx[6]=vb.z-mu; dx[7]=vb.w-mu;
    float s2 = 0.f;
#pragma unroll
    for (int i = 0; i < 8; ++i) s2 += dx[i] * dx[i];
    for (int off = 32; off; off >>= 1) s2 += __shfl_xor(s2, off);
    float rstd = rsqrtf(s2 * (1.0f / PD) + LN_EPS);
    float4 lw0 = *(const float4*)&lnw[j], lw1 = *(const float4*)&lnw[j + 4];
    float4 lb0 = *(const float4*)&lnb[j], lb1 = *(const float4*)&lnb[j + 4];
    float hln[8];
    hln[0]=fmaxf(dx[0]*rstd*lw0.x+lb0.x,0.f); hln[1]=fmaxf(dx[1]*rstd*lw0.y+lb0.y,0.f);
    hln[2]=fmaxf(dx[2]*rstd*lw0.z+lb0.z,0.f); hln[3]=fmaxf(dx[3]*rstd*lw0.w+lb0.w,0.f);
    hln[4]=fmaxf(dx[4]*rstd*lw1.x+lb1.x,0.f); hln[5]=fmaxf(dx[5]*rstd*lw1.y+lb1.y,0.f);
    hln[6]=fmaxf(dx[6]*rstd*lw1.z+lb1.z,0.f); hln[7]=fmaxf(dx[7]*rstd*lw1.w+lb1.w,0.f);
    const float* w = Wp2 + (size_t)row * PD + j;
    float4 w0 = *(const float4*)w, w1 = *(const float4*)(w + 4);
    float acc = w0.x*hln[0] + w0.y*hln[1] + w0.z*hln[2] + w0.w*hln[3]
              + w1.x*hln[4] + w1.y*hln[5] + w1.z*hln[6] + w1.w*hln[7];
    for (int off = 32; off; off >>= 1) acc += __shfl_xor(acc, off);
    if (lane == 0) x1f[row] = acc + bp2[row];
}

// out[s][j] = x[s][j] + x1f[j]; 2 float4/thread
__global__ __launch_bounds__(256) void k_out(const float* __restrict__ x,
                                             const float* __restrict__ x1f,
                                             float* __restrict__ out) {
    size_t i = (size_t)blockIdx.x * 512 + threadIdx.x;
    float4 xv = ((const float4*)x)[i];
    float4 a  = ((const float4*)x1f)[(int)(i & 511)];
    ((float4*)out)[i] = make_float4(xv.x + a.x, xv.y + a.y, xv.z + a.z, xv.w + a.w);
    size_t i2 = i + 256;
    float4 xv2 = ((const float4*)x)[i2];
    float4 a2  = ((const float4*)x1f)[(int)(i2 & 511)];
    ((float4*)out)[i2] = make_float4(xv2.x + a2.x, xv2.y + a2.y, xv2.z + a2.z, xv2.w + a2.w);
}

extern "C" void kernel_launch(void* const* d_in, const int* in_sizes, int n_in,
                              void* d_out, int out_size, void* d_ws, size_t ws_size,
                              hipStream_t stream) {
    const float* x    = (const float*)d_in[0];
    const float* q    = (const float*)d_in[1];
    const float* Wkv  = (const float*)d_in[2];
    const float* bkv  = (const float*)d_in[3];
    const float* Wp1  = (const float*)d_in[4];
    const float* bp1  = (const float*)d_in[5];
    const float* Wp2  = (const float*)d_in[6];
    const float* bp2  = (const float*)d_in[7];
    const float* lnw  = (const float*)d_in[8];
    const float* lnb  = (const float*)d_in[9];
    float* out = (float*)d_out;
    float* ws  = (float*)d_ws;

    float*  qb    = ws + OFF_QB;
    float*  smp   = ws + OFF_SMP;
    __bf16* qWb   = (__bf16*)(ws + OFF_QWB);
    float*  elogT = ws + OFF_ELOG;
    float*  pctx  = ws + OFF_PCTX;
    float*  ctx   = ws + OFF_CTX;
    float*  x1    = ws + OFF_X1;
    float*  h1raw = ws + OFF_H1R;
    float*  x1f   = ws + OFF_X1F;

    k_prep  <<<256, 256, 0, stream>>>(q, Wkv, bkv, qWb, qb, smp);
    k_logits<<<512, 256, 0, stream>>>(x, qWb, qb, elogT, smp);
    k_ctx   <<<512, 256, 0, stream>>>(x, elogT, smp, pctx);
    k_ctxred<<<128, 256, 0, stream>>>(pctx, ctx);
    k_x1    <<<512, 256, 0, stream>>>(Wkv, bkv, ctx, x1);
    k_h1    <<<128, 256, 0, stream>>>(Wp1, bp1, x1, h1raw);
    k_x1f   <<<512, 256, 0, stream>>>(Wp2, bp2, h1raw, lnw, lnb, x1f);
    k_out   <<<8192, 256, 0, stream>>>(x, x1f, out);
}